// Round 8
// baseline (506.185 us; speedup 1.0000x reference)
//
#include <hip/hip_runtime.h>
#include <hip/hip_bf16.h>
#include <cstdint>

#define NNODE 100000
#define NEDGE 500000
#define FIN   128
#define FHID  256
#define FOUT  128

// bucket-sort CSR parameters
#define NBUCK  1563   // ceil(NNODE/64)
#define CHUNK  2048
#define NCHUNK 245    // ceil(NEDGE/CHUNK)

typedef __attribute__((ext_vector_type(8))) short bf16x8;
typedef __attribute__((ext_vector_type(4))) float f32x4;

// ---------------------------------------------------------------- bf16 utils

__device__ inline unsigned short f2bf(float f) {
    unsigned int u = __float_as_uint(f);
    unsigned int r = (u + 0x7FFF + ((u >> 16) & 1)) >> 16;
    return (unsigned short)r;
}
__device__ inline float bf2f(unsigned short s) {
    return __uint_as_float(((unsigned int)s) << 16);
}
__device__ inline float bflo(unsigned int v) {   // low ushort -> float
    return __uint_as_float(v << 16);
}
__device__ inline float bfhi(unsigned int v) {   // high ushort -> float
    return __uint_as_float(v & 0xFFFF0000u);
}
__device__ inline void split2(float f, unsigned short& hi, unsigned short& lo) {
    hi = f2bf(f);
    lo = f2bf(f - bf2f(hi));
}

// ------------------------------------------------ atomic-free CSR build
// All coordination via LDS atomics; zero global atomics.

// P1: per-chunk LDS histograms over 64-node buckets (dst and src together)
__global__ __launch_bounds__(256)
void csr_count(const int* __restrict__ sb, const int* __restrict__ db,
               const int* __restrict__ sr, const int* __restrict__ dr,
               const int* __restrict__ sj, const int* __restrict__ dj,
               int* __restrict__ bh_dst, int* __restrict__ bh_src) {
    __shared__ int h1[NBUCK], h2[NBUCK];
    const int r = blockIdx.y, c = blockIdx.x, tid = threadIdx.x;
    const int* s = (r == 0) ? sb : (r == 1) ? sr : sj;
    const int* d = (r == 0) ? db : (r == 1) ? dr : dj;
    for (int i = tid; i < NBUCK; i += 256) { h1[i] = 0; h2[i] = 0; }
    __syncthreads();
    const int e0 = c * CHUNK;
#pragma unroll
    for (int i = 0; i < CHUNK / 256; ++i) {
        int e = e0 + i * 256 + tid;
        if (e < NEDGE) {
            atomicAdd(&h1[d[e] >> 6], 1);
            atomicAdd(&h2[s[e] >> 6], 1);
        }
    }
    __syncthreads();
    int* o1 = bh_dst + ((size_t)r * NCHUNK + c) * NBUCK;
    int* o2 = bh_src + ((size_t)r * NCHUNK + c) * NBUCK;
    for (int i = tid; i < NBUCK; i += 256) { o1[i] = h1[i]; o2[i] = h2[i]; }
}

// P2a: in-place exclusive scan over chunks (per bucket); emits bucket totals
__global__ void csr_scan_chunks(int* __restrict__ bh_dst, int* __restrict__ bh_src,
                                int* __restrict__ tot) {
    int idx = blockIdx.x * blockDim.x + threadIdx.x;
    if (idx >= 2 * 3 * NBUCK) return;
    int k = idx / (3 * NBUCK);
    int rem = idx - k * 3 * NBUCK;
    int r = rem / NBUCK;
    int b = rem - r * NBUCK;
    int* p = ((k == 0) ? bh_dst : bh_src) + (size_t)r * NCHUNK * NBUCK + b;
    int t = 0;
    int c = 0;
    for (; c + 4 <= NCHUNK; c += 4) {
        int v0 = p[0], v1 = p[NBUCK], v2 = p[2 * NBUCK], v3 = p[3 * NBUCK];
        p[0] = t; t += v0;
        p[NBUCK] = t; t += v1;
        p[2 * NBUCK] = t; t += v2;
        p[3 * NBUCK] = t; t += v3;
        p += 4 * NBUCK;
    }
    for (; c < NCHUNK; ++c) { int v = *p; *p = t; t += v; p += NBUCK; }
    tot[(k * 3 + r) * NBUCK + b] = t;
}

// P2b: exclusive scan over buckets -> bucket bases (incl. total at [NBUCK])
__global__ void csr_scan_buckets(const int* __restrict__ tot, int* __restrict__ bb) {
    const int k = blockIdx.x, r = blockIdx.y, tid = threadIdx.x;  // 256 thr
    const int base_in = (k * 3 + r) * NBUCK;
    const int base_out = (k * 3 + r) * (NBUCK + 1);
    int v[8];
    const int idx0 = tid * 8;
    int tsum = 0;
#pragma unroll
    for (int i = 0; i < 8; ++i) {
        int ii = idx0 + i;
        v[i] = (ii < NBUCK) ? tot[base_in + ii] : 0;
        tsum += v[i];
    }
    __shared__ int sm[256];
    sm[tid] = tsum;
    __syncthreads();
    for (int off = 1; off < 256; off <<= 1) {
        int t = 0;
        if (tid >= off) t = sm[tid - off];
        __syncthreads();
        sm[tid] += t;
        __syncthreads();
    }
    int run = sm[tid] - tsum;
#pragma unroll
    for (int i = 0; i < 8; ++i) {
        int ii = idx0 + i;
        if (ii <= NBUCK) bb[base_out + ii] = run;
        run += v[i];
    }
}

// P3: scatter edges into bucket-grouped buffers (LDS cursors, disjoint ranges)
__global__ __launch_bounds__(256)
void csr_scatter(const int* __restrict__ sb, const int* __restrict__ db,
                 const int* __restrict__ sr, const int* __restrict__ dr,
                 const int* __restrict__ sj, const int* __restrict__ dj,
                 const int* __restrict__ bh_dst, const int* __restrict__ bh_src,
                 const int* __restrict__ bb, unsigned int* __restrict__ ebd,
                 unsigned char* __restrict__ ebs) {
    __shared__ int cur1[NBUCK], cur2[NBUCK];
    const int r = blockIdx.y, c = blockIdx.x, tid = threadIdx.x;
    const int* s = (r == 0) ? sb : (r == 1) ? sr : sj;
    const int* d = (r == 0) ? db : (r == 1) ? dr : dj;
    const int* p1 = bh_dst + ((size_t)r * NCHUNK + c) * NBUCK;
    const int* p2 = bh_src + ((size_t)r * NCHUNK + c) * NBUCK;
    const int* bb1 = bb + r * (NBUCK + 1);              // dst section (k=0)
    const int* bb2 = bb + (3 + r) * (NBUCK + 1);        // src section (k=1)
    for (int i = tid; i < NBUCK; i += 256) {
        cur1[i] = bb1[i] + p1[i];
        cur2[i] = bb2[i] + p2[i];
    }
    __syncthreads();
    const int e0 = c * CHUNK;
#pragma unroll
    for (int i = 0; i < CHUNK / 256; ++i) {
        int e = e0 + i * 256 + tid;
        if (e < NEDGE) {
            int dv = d[e], sv = s[e];
            int q1 = atomicAdd(&cur1[dv >> 6], 1);
            ebd[(size_t)r * NEDGE + q1] = ((unsigned)(dv & 63) << 17) | (unsigned)sv;
            int q2 = atomicAdd(&cur2[sv >> 6], 1);
            ebs[(size_t)r * NEDGE + q2] = (unsigned char)(sv & 63);
        }
    }
}

// P4 (merged): dst finalize (rp, col, c_dst) + src count (c_src)
__global__ __launch_bounds__(256)
void csr_finalize(const unsigned int* __restrict__ ebd, const unsigned char* __restrict__ ebs,
                  const int* __restrict__ bb, int* __restrict__ rp, int* __restrict__ col,
                  float* __restrict__ c_src, float* __restrict__ c_dst) {
    __shared__ int hist[64], pref[64], cur[64];
    const int b = blockIdx.x, r = blockIdx.y, tid = threadIdx.x;
    const int* bb1 = bb + r * (NBUCK + 1);
    const int* bb2 = bb + (3 + r) * (NBUCK + 1);
    const int seg0 = bb1[b], seg1 = bb1[b + 1];
    if (tid < 64) hist[tid] = 0;
    __syncthreads();
    const unsigned int* eb = ebd + (size_t)r * NEDGE;
    for (int e = seg0 + tid; e < seg1; e += 256)
        atomicAdd(&hist[eb[e] >> 17], 1);
    __syncthreads();
    if (tid == 0) {
        int run = 0;
        for (int i = 0; i < 64; ++i) { pref[i] = run; run += hist[i]; }
    }
    __syncthreads();
    if (tid < 64) {
        int node = b * 64 + tid;
        if (node < NNODE) {
            rp[r * (NNODE + 1) + node] = seg0 + pref[tid];
            c_dst[r * NNODE + node] = rsqrtf((float)max(hist[tid], 1));
        }
        cur[tid] = seg0 + pref[tid];
    }
    if (b == 0 && tid == 0) rp[r * (NNODE + 1) + NNODE] = NEDGE;
    __syncthreads();
    for (int e = seg0 + tid; e < seg1; e += 256) {
        unsigned int key = eb[e];
        int pos = atomicAdd(&cur[key >> 17], 1);
        col[(size_t)r * NEDGE + pos] = (int)(key & 0x1FFFF);
    }
    // ---- src side (independent segment; reuse hist)
    __syncthreads();
    if (tid < 64) hist[tid] = 0;
    __syncthreads();
    const int t0 = bb2[b], t1 = bb2[b + 1];
    const unsigned char* es = ebs + (size_t)r * NEDGE;
    for (int e = t0 + tid; e < t1; e += 256)
        atomicAdd(&hist[es[e]], 1);
    __syncthreads();
    if (tid < 64) {
        int node = b * 64 + tid;
        if (node < NNODE) c_src[r * NNODE + node] = rsqrtf((float)max(hist[tid], 1));
    }
}

// ------------------------------------------- fused operand prep
// blocks [0,12500): x fp32->bf16 ; [12500,13268): 6 weight splits ; last: biases
#define XB_BLOCKS 12500   // NNODE*FIN/4/256

__global__ __launch_bounds__(256)
void prep_all(const float4* __restrict__ x4, ushort4* __restrict__ xb4,
              const float* __restrict__ W10, const float* __restrict__ W11,
              const float* __restrict__ W12, const float* __restrict__ W20,
              const float* __restrict__ W21, const float* __restrict__ W22,
              const float* __restrict__ b10, const float* __restrict__ b11,
              const float* __restrict__ b12, const float* __restrict__ b20,
              const float* __restrict__ b21, const float* __restrict__ b22,
              unsigned short* __restrict__ w1h, unsigned short* __restrict__ w1l,
              unsigned short* __restrict__ w2h, unsigned short* __restrict__ w2l,
              float* __restrict__ b1s, float* __restrict__ b2s) {
    int b = blockIdx.x;
    const int tid = threadIdx.x;
    if (b < XB_BLOCKS) {
        int i = b * 256 + tid;
        float4 v = x4[i];
        ushort4 o;
        o.x = f2bf(v.x); o.y = f2bf(v.y); o.z = f2bf(v.z); o.w = f2bf(v.w);
        xb4[i] = o;
        return;
    }
    b -= XB_BLOCKS;
    if (b < 768) {   // 6 tasks x 128 blocks; each task K*N = 32768
        int task = b >> 7;
        int i = ((b & 127) << 8) | tid;
        const float* W;
        unsigned short *th, *tl;
        int N, ldt, nbase, kbase;
        if (task < 3) {
            W = (task == 0) ? W10 : (task == 1) ? W11 : W12;
            th = w1h; tl = w1l; N = FHID; ldt = 3 * FIN; nbase = 0; kbase = task * FIN;
        } else {
            int r = task - 3;
            W = (r == 0) ? W20 : (r == 1) ? W21 : W22;
            th = w2h; tl = w2l; N = FOUT; ldt = FHID; nbase = r * FOUT; kbase = 0;
        }
        int k = i / N;
        int n = i - k * N;
        unsigned short hi, lo;
        split2(W[i], hi, lo);
        size_t o = (size_t)(nbase + n) * ldt + kbase + k;
        th[o] = hi;
        tl[o] = lo;
        return;
    }
    if (tid < FHID) b1s[tid] = b10[tid] + b11[tid] + b12[tid];
    if (tid < FOUT) b2s[tid] = b20[tid] + b21[tid] + b22[tid];
}

// --------------------------------------------------------------- SpMM (CSR)
// one wave per dst node; lane covers 2 feats (one dword).
// Scalarized edge loop: edge index j is wave-uniform -> readlane puts src id
// and weight into SGPRs; row address = SGPR base + lane voffset (SALU math,
// co-issues with VALU). Per edge per lane: 1 load + 2 unpack + 2 fmac.

__device__ inline void gather_rl(const char* __restrict__ rows, unsigned ldbytes,
                                 int sl, float wl, int cnt, int laneoff,
                                 float& ax, float& ay) {
    int j = 0;
    for (; j + 4 <= cnt; j += 4) {
        int s0 = __builtin_amdgcn_readlane(sl, j);
        int s1 = __builtin_amdgcn_readlane(sl, j + 1);
        int s2 = __builtin_amdgcn_readlane(sl, j + 2);
        int s3 = __builtin_amdgcn_readlane(sl, j + 3);
        float w0 = __uint_as_float(__builtin_amdgcn_readlane(__float_as_uint(wl), j));
        float w1 = __uint_as_float(__builtin_amdgcn_readlane(__float_as_uint(wl), j + 1));
        float w2 = __uint_as_float(__builtin_amdgcn_readlane(__float_as_uint(wl), j + 2));
        float w3 = __uint_as_float(__builtin_amdgcn_readlane(__float_as_uint(wl), j + 3));
        unsigned v0 = *(const unsigned*)(rows + (size_t)((unsigned)s0 * ldbytes) + laneoff);
        unsigned v1 = *(const unsigned*)(rows + (size_t)((unsigned)s1 * ldbytes) + laneoff);
        unsigned v2 = *(const unsigned*)(rows + (size_t)((unsigned)s2 * ldbytes) + laneoff);
        unsigned v3 = *(const unsigned*)(rows + (size_t)((unsigned)s3 * ldbytes) + laneoff);
        ax += w0 * bflo(v0); ay += w0 * bfhi(v0);
        ax += w1 * bflo(v1); ay += w1 * bfhi(v1);
        ax += w2 * bflo(v2); ay += w2 * bfhi(v2);
        ax += w3 * bflo(v3); ay += w3 * bfhi(v3);
    }
    for (; j < cnt; ++j) {
        int s = __builtin_amdgcn_readlane(sl, j);
        float w = __uint_as_float(__builtin_amdgcn_readlane(__float_as_uint(wl), j));
        unsigned v = *(const unsigned*)(rows + (size_t)((unsigned)s * ldbytes) + laneoff);
        ax += w * bflo(v); ay += w * bfhi(v);
    }
}

// deg > 64 fallback: reload 64 cols per chunk, same pattern
__device__ inline void gather_chunk(const char* __restrict__ rows, unsigned ldbytes,
                                    const int* __restrict__ colp,
                                    const float* __restrict__ csrc, int e0, int e1,
                                    int lane, int laneoff, float& ax, float& ay) {
    for (int base = e0; base < e1; base += 64) {
        int cnt = min(64, e1 - base);
        int sl = (lane < cnt) ? colp[base + lane] : 0;
        float wl = (lane < cnt) ? csrc[sl] : 0.f;
        gather_rl(rows, ldbytes, sl, wl, cnt, laneoff, ax, ay);
    }
}

__global__ __launch_bounds__(256)
void spmm1_all(const ushort2* __restrict__ xb, const int* __restrict__ rp,
               const int* __restrict__ col, const float* __restrict__ c_src,
               const float* __restrict__ c_dst, ushort2* __restrict__ agg) {
    int wid = (blockIdx.x * blockDim.x + threadIdx.x) >> 6;
    int lane = threadIdx.x & 63;
    if (wid >= NNODE) return;
    const int laneoff = lane * 4;
    int e0[3], e1[3], sl[3];
    float wl[3];
#pragma unroll
    for (int r = 0; r < 3; ++r) {
        e0[r] = rp[r * (NNODE + 1) + wid];
        e1[r] = rp[r * (NNODE + 1) + wid + 1];
    }
#pragma unroll
    for (int r = 0; r < 3; ++r) {
        int cnt = min(e1[r] - e0[r], 64);
        sl[r] = (lane < cnt) ? col[r * NEDGE + e0[r] + lane] : 0;
    }
#pragma unroll
    for (int r = 0; r < 3; ++r) {
        int cnt = min(e1[r] - e0[r], 64);
        wl[r] = (lane < cnt) ? c_src[r * NNODE + sl[r]] : 0.f;
    }
#pragma unroll
    for (int r = 0; r < 3; ++r) {
        float ax = 0.f, ay = 0.f;
        int cnt = min(e1[r] - e0[r], 64);
        gather_rl((const char*)xb, FIN * 2, sl[r], wl[r], cnt, laneoff, ax, ay);
        if (e0[r] + 64 < e1[r])
            gather_chunk((const char*)xb, FIN * 2, col + (size_t)r * NEDGE,
                         c_src + r * NNODE, e0[r] + 64, e1[r], lane, laneoff, ax, ay);
        float cd = c_dst[r * NNODE + wid];
        ushort2 o;
        o.x = f2bf(ax * cd);
        o.y = f2bf(ay * cd);
        agg[(size_t)wid * (3 * FIN / 2) + r * (FIN / 2) + lane] = o;  // [N][384] bf16
    }
}

__global__ __launch_bounds__(256)
void spmm2_all(const ushort2* __restrict__ yb, const int* __restrict__ rp,
               const int* __restrict__ col, const float* __restrict__ c_src,
               const float* __restrict__ c_dst, const float2* __restrict__ b2s2,
               float2* __restrict__ out2) {
    int wid = (blockIdx.x * blockDim.x + threadIdx.x) >> 6;
    int lane = threadIdx.x & 63;
    if (wid >= NNODE) return;
    const int laneoff = lane * 4;
    int e0[3], e1[3], sl[3];
    float wl[3];
#pragma unroll
    for (int r = 0; r < 3; ++r) {
        e0[r] = rp[r * (NNODE + 1) + wid];
        e1[r] = rp[r * (NNODE + 1) + wid + 1];
    }
#pragma unroll
    for (int r = 0; r < 3; ++r) {
        int cnt = min(e1[r] - e0[r], 64);
        sl[r] = (lane < cnt) ? col[r * NEDGE + e0[r] + lane] : 0;
    }
#pragma unroll
    for (int r = 0; r < 3; ++r) {
        int cnt = min(e1[r] - e0[r], 64);
        wl[r] = (lane < cnt) ? c_src[r * NNODE + sl[r]] : 0.f;
    }
    float2 acc = b2s2[lane];
#pragma unroll
    for (int r = 0; r < 3; ++r) {
        const char* rows = (const char*)(yb + r * (FOUT / 2));  // stride 3*FOUT*2 B
        float ax = 0.f, ay = 0.f;
        int cnt = min(e1[r] - e0[r], 64);
        gather_rl(rows, 3 * FOUT * 2, sl[r], wl[r], cnt, laneoff, ax, ay);
        if (e0[r] + 64 < e1[r])
            gather_chunk(rows, 3 * FOUT * 2, col + (size_t)r * NEDGE,
                         c_src + r * NNODE, e0[r] + 64, e1[r], lane, laneoff, ax, ay);
        float cd = c_dst[r * NNODE + wid];
        acc.x += cd * ax;
        acc.y += cd * ay;
    }
    out2[(size_t)wid * (FOUT / 2) + lane] = acc;
}

// ------------------------------------------------------------ MFMA GEMM
// C[M][N] = A[M][K](bf16) @ B, B pre-transposed [N][K] hi/lo bf16.
// acc += A*Bh + A*Bl. 128x128 tile, BK=32, 4 waves 2x2, 4x4 frags 16x16x32.
// EPI 0: C = relu(acc + bias) -> bf16.  EPI 1: C = acc -> bf16.

template <int K, int EPI>
__global__ __launch_bounds__(256)
void gemm_bf16(const unsigned short* __restrict__ A, const unsigned short* __restrict__ Bh,
               const unsigned short* __restrict__ Bl, const float* __restrict__ bias,
               unsigned short* __restrict__ C, int M, int N) {
    __shared__ unsigned short As[128][40];
    __shared__ unsigned short Bsh[128][40];
    __shared__ unsigned short Bsl[128][40];
    const int bm = blockIdx.x * 128;
    const int bn = blockIdx.y * 128;
    const int tid = threadIdx.x;
    const int lane = tid & 63;
    const int wv = tid >> 6;
    const int wm = (wv >> 1) * 64;
    const int wn = (wv & 1) * 64;

    const int srow = tid >> 1;        // 0..127
    const int scol = (tid & 1) * 16;  // shorts
    const size_t abase = (size_t)(bm + srow) * K + scol;
    const size_t bbase = (size_t)(bn + srow) * K + scol;
    const bool avalid = (bm + srow) < M;

    f32x4 acc[4][4] = {};

    for (int k0 = 0; k0 < K; k0 += 32) {
        uint4 z = make_uint4(0, 0, 0, 0);
        uint4 a0 = z, a1 = z;
        if (avalid) {
            a0 = *(const uint4*)&A[abase + k0];
            a1 = *(const uint4*)&A[abase + k0 + 8];
        }
        uint4 b0 = *(const uint4*)&Bh[bbase + k0];
        uint4 b1 = *(const uint4*)&Bh[bbase + k0 + 8];
        uint4 m0 = *(const uint4*)&Bl[bbase + k0];
        uint4 m1 = *(const uint4*)&Bl[bbase + k0 + 8];
        *(uint4*)&As[srow][scol] = a0;
        *(uint4*)&As[srow][scol + 8] = a1;
        *(uint4*)&Bsh[srow][scol] = b0;
        *(uint4*)&Bsh[srow][scol + 8] = b1;
        *(uint4*)&Bsl[srow][scol] = m0;
        *(uint4*)&Bsl[srow][scol + 8] = m1;
        __syncthreads();

        const int kb = (lane >> 4) * 8;
        const int fr = lane & 15;
        bf16x8 a[4], bh[4], bl[4];
#pragma unroll
        for (int i = 0; i < 4; ++i) {
            a[i] = *(const bf16x8*)&As[wm + i * 16 + fr][kb];
            bh[i] = *(const bf16x8*)&Bsh[wn + i * 16 + fr][kb];
            bl[i] = *(const bf16x8*)&Bsl[wn + i * 16 + fr][kb];
        }
#pragma unroll
        for (int mi = 0; mi < 4; ++mi)
#pragma unroll
            for (int ni = 0; ni < 4; ++ni) {
                acc[mi][ni] = __builtin_amdgcn_mfma_f32_16x16x32_bf16(a[mi], bh[ni], acc[mi][ni], 0, 0, 0);
                acc[mi][ni] = __builtin_amdgcn_mfma_f32_16x16x32_bf16(a[mi], bl[ni], acc[mi][ni], 0, 0, 0);
            }
        __syncthreads();
    }

    // epilogue: C/D map col=lane&15, row=(lane>>4)*4+reg
    const int cl = lane & 15;
    const int rl = (lane >> 4) * 4;
#pragma unroll
    for (int mi = 0; mi < 4; ++mi) {
#pragma unroll
        for (int ni = 0; ni < 4; ++ni) {
            const int gcol = bn + wn + ni * 16 + cl;
            float bv = (EPI == 0) ? bias[gcol] : 0.f;
#pragma unroll
            for (int rg = 0; rg < 4; ++rg) {
                const int grow = bm + wm + mi * 16 + rl + rg;
                if (grow < M) {
                    float v = acc[mi][ni][rg];
                    if (EPI == 0) v = fmaxf(v + bv, 0.f);
                    C[(size_t)grow * N + gcol] = f2bf(v);
                }
            }
        }
    }
}

// ---------------------------------------------------------------- launcher

extern "C" void kernel_launch(void* const* d_in, const int* in_sizes, int n_in,
                              void* d_out, int out_size, void* d_ws, size_t ws_size,
                              hipStream_t stream) {
    const float* x = (const float*)d_in[0];
    const int* src_b = (const int*)d_in[1];
    const int* dst_b = (const int*)d_in[2];
    const int* src_r = (const int*)d_in[3];
    const int* dst_r = (const int*)d_in[4];
    const int* src_j = (const int*)d_in[5];
    const int* dst_j = (const int*)d_in[6];
    const float* W1[3] = {(const float*)d_in[7], (const float*)d_in[11], (const float*)d_in[15]};
    const float* b1[3] = {(const float*)d_in[8], (const float*)d_in[12], (const float*)d_in[16]};
    const float* W2[3] = {(const float*)d_in[9], (const float*)d_in[13], (const float*)d_in[17]};
    const float* b2[3] = {(const float*)d_in[10], (const float*)d_in[14], (const float*)d_in[18]};
    float* out = (float*)d_out;

    char* w = (char*)d_ws;
    auto alloc = [&](size_t bytes) -> char* {
        char* p = w;
        w += (bytes + 255) & ~(size_t)255;
        return p;
    };
    float* c_src = (float*)alloc((size_t)3 * NNODE * 4);
    float* c_dst = (float*)alloc((size_t)3 * NNODE * 4);
    int* rp = (int*)alloc((size_t)3 * (NNODE + 1) * 4);
    int* tot = (int*)alloc((size_t)2 * 3 * NBUCK * 4);
    int* bb = (int*)alloc((size_t)2 * 3 * (NBUCK + 1) * 4);
    int* col = (int*)alloc((size_t)3 * NEDGE * 4);
    float* b1s = (float*)alloc(FHID * 4);
    float* b2s = (float*)alloc(FOUT * 4);
    unsigned short* wpl = (unsigned short*)alloc((size_t)4 * 98304 * 2);  // 786 KB
    unsigned short* w1h = wpl;                     // [256][384]
    unsigned short* w1l = w1h + FHID * 3 * FIN;
    unsigned short* w2h = w1l + FHID * 3 * FIN;    // [384][256]
    unsigned short* w2l = w2h + 3 * FOUT * FHID;
    unsigned short* xbf = (unsigned short*)alloc((size_t)NNODE * FIN * 2);        // [N][128] bf16
    unsigned short* aggcat = (unsigned short*)alloc((size_t)NNODE * 3 * FIN * 2); // [N][384] bf16
    unsigned short* ycat = aggcat;  // aliased: aggcat dead after L1 GEMM
    unsigned short* hb = (unsigned short*)alloc((size_t)NNODE * FHID * 2);        // [N][256] bf16

    // CSR-build scratch aliased inside aggcat (76.8 MB; dead until spmm1):
    char* sc = (char*)aggcat;
    int* bh_dst = (int*)sc;                  sc += (size_t)3 * NCHUNK * NBUCK * 4;  // 4.6 MB
    int* bh_src = (int*)sc;                  sc += (size_t)3 * NCHUNK * NBUCK * 4;  // 4.6 MB
    unsigned int* ebd = (unsigned int*)sc;   sc += (size_t)3 * NEDGE * 4;           // 6 MB
    unsigned char* ebs = (unsigned char*)sc; sc += (size_t)3 * NEDGE;               // 1.5 MB

    const int T = 256;

    // 1. atomic-free bucket-sorted CSR build (c_src/c_dst/rp/col all direct)
    csr_count<<<dim3(NCHUNK, 3), T, 0, stream>>>(
        src_b, dst_b, src_r, dst_r, src_j, dst_j, bh_dst, bh_src);
    csr_scan_chunks<<<dim3((2 * 3 * NBUCK + T - 1) / T), T, 0, stream>>>(bh_dst, bh_src, tot);
    csr_scan_buckets<<<dim3(2, 3), T, 0, stream>>>(tot, bb);
    csr_scatter<<<dim3(NCHUNK, 3), T, 0, stream>>>(
        src_b, dst_b, src_r, dst_r, src_j, dst_j, bh_dst, bh_src, bb, ebd, ebs);
    csr_finalize<<<dim3(NBUCK, 3), T, 0, stream>>>(ebd, ebs, bb, rp, col, c_src, c_dst);

    // 2. fused operand prep (x->bf16, 6 weight splits, bias sums)
    prep_all<<<dim3(XB_BLOCKS + 768 + 1), T, 0, stream>>>(
        (const float4*)x, (ushort4*)xbf,
        W1[0], W1[1], W1[2], W2[0], W2[1], W2[2],
        b1[0], b1[1], b1[2], b2[0], b2[1], b2[2],
        w1h, w1l, w2h, w2l, b1s, b2s);

    const dim3 spmm_grid((NNODE * 64 + T - 1) / T);

    // 3. layer 1: aggregate all relations -> aggcat [N,384] bf16, one GEMM -> h bf16
    spmm1_all<<<spmm_grid, T, 0, stream>>>(
        (const ushort2*)xbf, rp, col, c_src, c_dst, (ushort2*)aggcat);
    gemm_bf16<3 * FIN, 0><<<dim3((NNODE + 127) / 128, FHID / 128), 256, 0, stream>>>(
        aggcat, w1h, w1l, b1s, hb, NNODE, FHID);

    // 4. layer 2: one GEMM h @ [W2_b|W2_r|W2_j] -> ycat [N,384] bf16, aggregate -> out
    gemm_bf16<FHID, 1><<<dim3((NNODE + 127) / 128, (3 * FOUT) / 128), 256, 0, stream>>>(
        hb, w2h, w2l, nullptr, ycat, NNODE, 3 * FOUT);
    spmm2_all<<<spmm_grid, T, 0, stream>>>(
        (const ushort2*)ycat, rp, col, c_src, c_dst, (const float2*)b2s, (float2*)out);
}